// Round 1
// baseline (482.763 us; speedup 1.0000x reference)
//
#include <hip/hip_runtime.h>

#define BATCH 16
#define SEQ   4096
#define HEADS 16
#define EMB   64
#define SS    64      // s = sqrt(SEQ)
#define NW    127     // 2*s - 1

// One block per (b,h). 512 threads = 8 waves. lane = e (EMB index).
// Wave w owns rows i in [8w, 8w+8).
__global__ __launch_bounds__(512) void pbv_kernel(const float* __restrict__ v,
                                                  const float* __restrict__ w,
                                                  float* __restrict__ out) {
    __shared__ float us [SS][SS];   // [i][e] : u_s, later RxU
    __shared__ float vsf[SS][SS];   // [j][e] : v_s, later RxV
    __shared__ float wtab[NW];

    const int bh   = blockIdx.x;
    const int b    = bh / HEADS;
    const int h    = bh % HEADS;
    const int tid  = threadIdx.x;
    const int wave = tid >> 6;      // 0..7
    const int lane = tid & 63;      // e

    // zero v_s accumulator target, stage w[h,:]
    for (int idx = tid; idx < SS * SS; idx += 512) (&vsf[0][0])[idx] = 0.0f;
    if (tid < NW) wtab[tid] = w[h * NW + tid];
    __syncthreads();

    // ---- phase 1: row/col sums ----
    const float* vbase = v + ((size_t)b * SEQ * HEADS + h) * EMB + lane;
    float vsacc[SS];
    #pragma unroll
    for (int j = 0; j < SS; ++j) vsacc[j] = 0.0f;

    for (int ii = 0; ii < 8; ++ii) {
        const int i = wave * 8 + ii;
        const float* rowp = vbase + (size_t)i * SS * (HEADS * EMB);
        float uacc = 0.0f;
        #pragma unroll
        for (int j = 0; j < SS; ++j) {
            float val = rowp[(size_t)j * (HEADS * EMB)];
            uacc += val;
            vsacc[j] += val;
        }
        us[i][lane] = uacc;
    }
    // merge per-wave v_s partials (vsf was zeroed & synced above)
    #pragma unroll
    for (int j = 0; j < SS; ++j) atomicAdd(&vsf[j][lane], vsacc[j]);
    __syncthreads();

    // ---- phase 2: circular conv with w (64x64 Toeplitz matvec per e-lane) ----
    // RxV[t][e] = sum_j wtab[(t-j+64)%127] * v_s[j][e]; same for RxU from u_s.
    float rv[8], ru[8];
    for (int tt = 0; tt < 8; ++tt) {
        const int t = wave * 8 + tt;
        float accv = 0.0f, accu = 0.0f;
        #pragma unroll
        for (int j = 0; j < SS; ++j) {
            int k = t - j + 64;          // in [1,127]
            if (k >= NW) k -= NW;
            const float c = wtab[k];
            accv += c * vsf[j][lane];
            accu += c * us [j][lane];
        }
        rv[tt] = accv;
        ru[tt] = accu;
    }
    __syncthreads();   // all reads of vsf/us done before overwrite
    for (int tt = 0; tt < 8; ++tt) {
        const int t = wave * 8 + tt;
        vsf[t][lane] = rv[tt];   // RxV
        us [t][lane] = ru[tt];   // RxU
    }
    __syncthreads();

    // ---- phase 3: expand & write: out[b, i*64+j, h, e] = RxV[j][e] + RxU[i][e]
    float* obase = out + ((size_t)b * SEQ * HEADS + h) * EMB + lane;
    for (int ii = 0; ii < 8; ++ii) {
        const int i = wave * 8 + ii;
        const float ruv = us[i][lane];
        #pragma unroll
        for (int j = 0; j < SS; ++j) {
            obase[(size_t)(i * SS + j) * (HEADS * EMB)] = vsf[j][lane] + ruv;
        }
    }
}

// z_pb: zp[h][t] = s * sum_j o_[j] * w[h, (t-j+64)%127]
// out2[0, i*64+j, h] = zp[h][j] + zp[h][i].  Grid: 64 blocks (one per i).
__global__ __launch_bounds__(256) void zpb_kernel(const float* __restrict__ w,
                                                  const float* __restrict__ o_,
                                                  float* __restrict__ out2) {
    __shared__ float zp[HEADS][SS];
    __shared__ float osh[SS];
    __shared__ float wsh[HEADS * NW];

    const int tid = threadIdx.x;
    const int g   = blockIdx.x;   // i index

    if (tid < SS) osh[tid] = o_[tid];
    for (int idx = tid; idx < HEADS * NW; idx += 256) wsh[idx] = w[idx];
    __syncthreads();

    for (int idx = tid; idx < HEADS * SS; idx += 256) {
        const int h = idx / SS, t = idx % SS;
        float acc = 0.0f;
        #pragma unroll
        for (int j = 0; j < SS; ++j) {
            int k = t - j + 64;
            if (k >= NW) k -= NW;
            acc += osh[j] * wsh[h * NW + k];
        }
        zp[h][t] = acc * (float)SS;
    }
    __syncthreads();

    for (int idx = tid; idx < SS * HEADS; idx += 256) {
        const int tl = idx / HEADS, h = idx % HEADS;
        out2[(size_t)(g * SS + tl) * HEADS + h] = zp[h][tl] + zp[h][g];
    }
}

extern "C" void kernel_launch(void* const* d_in, const int* in_sizes, int n_in,
                              void* d_out, int out_size, void* d_ws, size_t ws_size,
                              hipStream_t stream) {
    const float* v  = (const float*)d_in[0];
    const float* w  = (const float*)d_in[1];
    const float* o_ = (const float*)d_in[2];
    float* out = (float*)d_out;

    pbv_kernel<<<BATCH * HEADS, 512, 0, stream>>>(v, w, out);

    const size_t out1_elems = (size_t)BATCH * SEQ * HEADS * EMB;
    zpb_kernel<<<SS, 256, 0, stream>>>(w, o_, out + out1_elems);
}